// Round 1
// baseline (1238.074 us; speedup 1.0000x reference)
//
#include <hip/hip_runtime.h>

#define NTH 64

__device__ __forceinline__ float sigmoidf_(float x) {
    return 1.0f / (1.0f + __expf(-x));
}
__device__ __forceinline__ float tanhf_(float x) {
    // tanh(x) = 1 - 2/(exp(2x)+1); saturates correctly at +/-inf
    return 1.0f - 2.0f / (1.0f + __expf(2.0f * x));
}

// ---------------------------------------------------------------------------
// Precompute:
//  gio[o][n]  = b_ih[n] + (n<200 ? b_hh[n] : 0) + obs[o] . W_ih[n, 0:100]
//  Wt[k][n]   = k<18 ? W_ih[n][100+k] : W_hh[n][k-18]   (transposed, contiguous in n)
//  W1T[g][j]  = W1[j][g]
//  W2T[j][i]  = W2[i][j]
// ---------------------------------------------------------------------------
__global__ __launch_bounds__(64) void precompute_kernel(
    const float* __restrict__ obs, const float* __restrict__ W_ih,
    const float* __restrict__ W_hh, const float* __restrict__ b_ih,
    const float* __restrict__ b_hh, const float* __restrict__ W1,
    const float* __restrict__ W2,
    float* __restrict__ gio, float* __restrict__ Wt,
    float* __restrict__ W1T, float* __restrict__ W2T)
{
    int t = blockIdx.x * NTH + threadIdx.x;
    if (t < 19200) {
        int o = t / 300, n = t % 300;
        float a = b_ih[n] + (n < 200 ? b_hh[n] : 0.0f);
        const float* orow = obs + o * 100;
        const float* wrow = W_ih + n * 118;
        for (int k = 0; k < 100; ++k) a = fmaf(orow[k], wrow[k], a);
        gio[t] = a;
        return;
    }
    t -= 19200;
    if (t < 35400) {
        int k = t / 300, n = t % 300;
        Wt[t] = (k < 18) ? W_ih[n * 118 + 100 + k] : W_hh[n * 100 + (k - 18)];
        return;
    }
    t -= 35400;
    if (t < 5000) { // W1: (50,100) -> W1T[g*50+j]
        int g = t / 50, j = t % 50;
        W1T[t] = W1[j * 100 + g];
        return;
    }
    t -= 5000;
    if (t < 1250) { // W2: (25,50) -> W2T[j*25+i]
        int j = t / 25, i = t % 25;
        W2T[t] = W2[i * 50 + j];
    }
}

// ---------------------------------------------------------------------------
// One tree level. Thread = one (o,p,node) cell.
// h buffers are stored transposed: h[g][cell], cell = op*w + j.
// Non-last levels store the PAIR-SUM (h_child for next level), halving traffic.
// ---------------------------------------------------------------------------
__global__ __launch_bounds__(64) void gru_level(
    const float* __restrict__ gio,   // [64][300], biases folded (r,z: b_ih+b_hh; n: b_ih)
    const float* __restrict__ Wt,    // [118][300]
    const float* __restrict__ bhhn,  // b_hh + 200 (n-gate hidden bias, applied inside r*(...))
    const float* __restrict__ samp,  // (O,P,N,8)
    const float* __restrict__ addr,  // (O,P,N,10)
    const float* __restrict__ hin,   // [100][cells]  (h_child; unused when first)
    float* __restrict__ hout,        // [100][cells/2] pairsum, or [100][cells] when last
    int lw, int first, int last)
{
    const int c = blockIdx.x * NTH + threadIdx.x;
    const int w = 1 << lw;
    const int cells = 4096 << lw;
    const int op = c >> lw;
    const int j = c & (w - 1);
    const int node = w - 1 + j;
    const int o = op >> 6;

    const float* sp = samp + ((size_t)(op * 63 + node)) * 8;
    const float* ap = addr + ((size_t)(op * 63 + node)) * 10;
    const float* giob = gio + o * 300;
    const float* hc = hin + c;

    float acc[100];
    float carry[100];

    // ---------------- pass 1: r gate (offset 0) ----------------
    #pragma unroll
    for (int g = 0; g < 100; ++g) acc[g] = giob[g];
    #pragma unroll 1
    for (int k = 0; k < 8; ++k) {
        float xk = sp[k];
        const float* wr = Wt + k * 300;
        #pragma unroll
        for (int g = 0; g < 100; ++g) acc[g] = fmaf(xk, wr[g], acc[g]);
    }
    #pragma unroll 1
    for (int k = 0; k < 10; ++k) {
        float xk = ap[k];
        const float* wr = Wt + (8 + k) * 300;
        #pragma unroll
        for (int g = 0; g < 100; ++g) acc[g] = fmaf(xk, wr[g], acc[g]);
    }
    if (!first) {
        #pragma unroll 2
        for (int k = 0; k < 100; ++k) {
            float hk = hc[(size_t)k * cells];
            const float* wr = Wt + (18 + k) * 300;
            #pragma unroll
            for (int g = 0; g < 100; ++g) acc[g] = fmaf(hk, wr[g], acc[g]);
        }
    }
    #pragma unroll
    for (int g = 0; g < 100; ++g) carry[g] = sigmoidf_(acc[g]);  // carry = r

    // ---------------- pass 2: hidden part of n gate (offset 200) ----------------
    #pragma unroll
    for (int g = 0; g < 100; ++g) acc[g] = bhhn[g];
    if (!first) {
        #pragma unroll 2
        for (int k = 0; k < 100; ++k) {
            float hk = hc[(size_t)k * cells];
            const float* wr = Wt + (18 + k) * 300 + 200;
            #pragma unroll
            for (int g = 0; g < 100; ++g) acc[g] = fmaf(hk, wr[g], acc[g]);
        }
    }
    #pragma unroll
    for (int g = 0; g < 100; ++g) carry[g] *= acc[g];  // carry = r * h_n

    // ---------------- pass 3: input part of n gate (offset 200) ----------------
    #pragma unroll
    for (int g = 0; g < 100; ++g) acc[g] = giob[200 + g];
    #pragma unroll 1
    for (int k = 0; k < 8; ++k) {
        float xk = sp[k];
        const float* wr = Wt + k * 300 + 200;
        #pragma unroll
        for (int g = 0; g < 100; ++g) acc[g] = fmaf(xk, wr[g], acc[g]);
    }
    #pragma unroll 1
    for (int k = 0; k < 10; ++k) {
        float xk = ap[k];
        const float* wr = Wt + (8 + k) * 300 + 200;
        #pragma unroll
        for (int g = 0; g < 100; ++g) acc[g] = fmaf(xk, wr[g], acc[g]);
    }
    #pragma unroll
    for (int g = 0; g < 100; ++g) carry[g] = tanhf_(acc[g] + carry[g]);  // carry = n

    // ---------------- pass 4: z gate (offset 100) + epilogue ----------------
    #pragma unroll
    for (int g = 0; g < 100; ++g) acc[g] = giob[100 + g];
    #pragma unroll 1
    for (int k = 0; k < 8; ++k) {
        float xk = sp[k];
        const float* wr = Wt + k * 300 + 100;
        #pragma unroll
        for (int g = 0; g < 100; ++g) acc[g] = fmaf(xk, wr[g], acc[g]);
    }
    #pragma unroll 1
    for (int k = 0; k < 10; ++k) {
        float xk = ap[k];
        const float* wr = Wt + (8 + k) * 300 + 100;
        #pragma unroll
        for (int g = 0; g < 100; ++g) acc[g] = fmaf(xk, wr[g], acc[g]);
    }
    if (!first) {
        #pragma unroll 2
        for (int k = 0; k < 100; ++k) {
            float hk = hc[(size_t)k * cells];
            const float* wr = Wt + (18 + k) * 300 + 100;
            #pragma unroll
            for (int g = 0; g < 100; ++g) acc[g] = fmaf(hk, wr[g], acc[g]);
        }
    }

    const int half = cells >> 1;
    #pragma unroll
    for (int g = 0; g < 100; ++g) {
        float z = sigmoidf_(acc[g]);
        float hcv = first ? 0.0f : hc[(size_t)g * cells];
        float hv = (1.0f - z) * carry[g] + z * hcv;
        if (last) {
            hout[(size_t)g * cells + c] = hv;
        } else {
            float hs = hv + __shfl_xor(hv, 1);
            if ((c & 1) == 0) hout[(size_t)g * half + (c >> 1)] = hs;
        }
    }
}

// ---------------------------------------------------------------------------
// MLP head + logsumexp over the 64 particles. Block = one o (64 lanes = particles).
// ---------------------------------------------------------------------------
__global__ __launch_bounds__(64) void mlp_lse(
    const float* __restrict__ h0,   // [100][4096]
    const float* __restrict__ W1T,  // [100][50]
    const float* __restrict__ b1,
    const float* __restrict__ W2T,  // [50][25]
    const float* __restrict__ b2,
    const float* __restrict__ W3,   // [25]
    const float* __restrict__ b3,
    float* __restrict__ out)
{
    const int o = blockIdx.x;
    const int p = threadIdx.x;
    const int c = o * 64 + p;

    float y1[50];
    #pragma unroll
    for (int j = 0; j < 50; ++j) y1[j] = b1[j];
    #pragma unroll 2
    for (int g = 0; g < 100; ++g) {
        float rg = h0[(size_t)g * 4096 + c];
        const float* wr = W1T + g * 50;
        #pragma unroll
        for (int j = 0; j < 50; ++j) y1[j] = fmaf(rg, wr[j], y1[j]);
    }

    float y2[25];
    #pragma unroll
    for (int i = 0; i < 25; ++i) y2[i] = b2[i];
    #pragma unroll
    for (int j = 0; j < 50; ++j) {
        float v = fmaxf(y1[j], 0.0f);
        const float* wr = W2T + j * 25;
        #pragma unroll
        for (int i = 0; i < 25; ++i) y2[i] = fmaf(v, wr[i], y2[i]);
    }

    float cv = b3[0];
    #pragma unroll
    for (int i = 0; i < 25; ++i) cv = fmaf(fmaxf(y2[i], 0.0f), W3[i], cv);

    // logsumexp over 64 lanes
    float m = cv;
    #pragma unroll
    for (int s = 1; s < 64; s <<= 1) m = fmaxf(m, __shfl_xor(m, s));
    float e = __expf(cv - m);
    #pragma unroll
    for (int s = 1; s < 64; s <<= 1) e += __shfl_xor(e, s);
    if (p == 0) out[o] = m + __logf(e) - 4.1588830833596715f; // log(64)
}

// ---------------------------------------------------------------------------
extern "C" void kernel_launch(void* const* d_in, const int* in_sizes, int n_in,
                              void* d_out, int out_size, void* d_ws, size_t ws_size,
                              hipStream_t stream)
{
    const float* obs  = (const float*)d_in[0];
    const float* samp = (const float*)d_in[1];
    const float* addr = (const float*)d_in[2];
    const float* W_ih = (const float*)d_in[3];
    const float* W_hh = (const float*)d_in[4];
    const float* b_ih = (const float*)d_in[5];
    const float* b_hh = (const float*)d_in[6];
    const float* W1   = (const float*)d_in[7];
    const float* b1   = (const float*)d_in[8];
    const float* W2   = (const float*)d_in[9];
    const float* b2   = (const float*)d_in[10];
    const float* W3   = (const float*)d_in[11];
    const float* b3   = (const float*)d_in[12];
    float* out = (float*)d_out;

    float* ws  = (float*)d_ws;
    float* gio = ws;             // 19200
    float* Wt  = ws + 19200;     // 35400
    float* W1T = ws + 54600;     // 5000
    float* W2T = ws + 59600;     // 1250
    float* hA  = ws + 60864;     // 100 * 65536 = 6,553,600 floats
    float* hB  = hA + 6553600;   // 100 * 32768 = 3,276,800 floats

    precompute_kernel<<<(60850 + NTH - 1) / NTH, NTH, 0, stream>>>(
        obs, W_ih, W_hh, b_ih, b_hh, W1, W2, gio, Wt, W1T, W2T);

    struct Lv { int lw; const float* hin; float* hout; int first; int last; };
    const Lv L[6] = {
        {5, hA, hA, 1, 0},   // level 5: h_child = 0, writes pairsum -> hA [100][65536]
        {4, hA, hB, 0, 0},   // -> hB [100][32768]
        {3, hB, hA, 0, 0},   // -> hA [100][16384]
        {2, hA, hB, 0, 0},   // -> hB [100][8192]
        {1, hB, hA, 0, 0},   // -> hA [100][4096]  (root's h_child)
        {0, hA, hB, 0, 1},   // root h -> hB [100][4096]
    };
    for (int i = 0; i < 6; ++i) {
        int cells = 4096 << L[i].lw;
        gru_level<<<cells / NTH, NTH, 0, stream>>>(
            gio, Wt, b_hh + 200, samp, addr,
            L[i].hin, L[i].hout, L[i].lw, L[i].first, L[i].last);
    }

    mlp_lse<<<64, NTH, 0, stream>>>(hB, W1T, b1, W2T, b2, W3, b3, out);
}

// Round 2
// 380.826 us; speedup vs baseline: 3.2510x; 3.2510x over previous
//
#include <hip/hip_runtime.h>

#define NTH 64

__device__ __forceinline__ float sigmoidf_(float x) {
    return 1.0f / (1.0f + __expf(-x));
}
__device__ __forceinline__ float tanhf_(float x) {
    return 1.0f - 2.0f / (1.0f + __expf(2.0f * x));
}

// ---------------------------------------------------------------------------
// Weight repacking (slice = g/25, i = g%25, grp: 0=r,1=z,2=n):
//  giop[o][slice*75 + grp*25 + i] = b_ih[gate] + (grp<2? b_hh[gate]:0) + obs[o].W_ih[gate,:100]
//  Whp [k][slice*75 + grp*25 + i] = W_hh[gate][k]                (k<100)
//  Wirz[k][slice*50 + grp*25 + i] = W_ih[gate][100+k], grp<2     (k<18)
//  Win [k][slice*25 + i]          = W_ih[200+g][100+k]           (k<18)
//  bhhp[g] = b_hh[200+g]
//  gate = grp*100 + slice*25 + i
// ---------------------------------------------------------------------------
__global__ __launch_bounds__(64) void precompute_kernel(
    const float* __restrict__ obs, const float* __restrict__ W_ih,
    const float* __restrict__ W_hh, const float* __restrict__ b_ih,
    const float* __restrict__ b_hh, const float* __restrict__ W1,
    const float* __restrict__ W2,
    float* __restrict__ giop, float* __restrict__ Whp,
    float* __restrict__ Wirz, float* __restrict__ Win,
    float* __restrict__ bhhp, float* __restrict__ W1T, float* __restrict__ W2T)
{
    int t = blockIdx.x * NTH + threadIdx.x;
    if (t < 19200) { // giop
        int o = t / 300, r = t % 300;
        int slice = r / 75, q = r % 75, grp = q / 25, i = q % 25;
        int gate = grp * 100 + slice * 25 + i;
        float a = b_ih[gate] + (grp < 2 ? b_hh[gate] : 0.0f);
        const float* orow = obs + o * 100;
        const float* wrow = W_ih + gate * 118;
        for (int k = 0; k < 100; ++k) a = fmaf(orow[k], wrow[k], a);
        giop[t] = a;
        return;
    }
    t -= 19200;
    if (t < 30000) { // Whp
        int k = t / 300, r = t % 300;
        int slice = r / 75, q = r % 75, grp = q / 25, i = q % 25;
        int gate = grp * 100 + slice * 25 + i;
        Whp[t] = W_hh[gate * 100 + k];
        return;
    }
    t -= 30000;
    if (t < 3600) { // Wirz
        int k = t / 200, r = t % 200;
        int slice = r / 50, q = r % 50, grp = q / 25, i = q % 25;
        int gate = grp * 100 + slice * 25 + i;
        Wirz[t] = W_ih[gate * 118 + 100 + k];
        return;
    }
    t -= 3600;
    if (t < 1800) { // Win
        int k = t / 100, g = t % 100;
        Win[t] = W_ih[(200 + g) * 118 + 100 + k];
        return;
    }
    t -= 1800;
    if (t < 100) { bhhp[t] = b_hh[200 + t]; return; }
    t -= 100;
    if (t < 5000) { // W1T[g*50+j] = W1[j*100+g]
        int g = t / 50, j = t % 50;
        W1T[t] = W1[j * 100 + g];
        return;
    }
    t -= 5000;
    if (t < 1250) { // W2T[j*25+i] = W2[i*50+j]
        int j = t / 25, i = t % 25;
        W2T[t] = W2[i * 50 + j];
    }
}

// ---------------------------------------------------------------------------
// One tree level. Lane = cell, blockIdx.y = g-slice (25 gates of each of r/z/n).
// Single fused k-loop over the 100 hidden inputs accumulating r,z,nh at once:
// h read once per k, weights wave-uniform (SGPR broadcast).
// h buffers transposed: h[g][cell]. Non-last levels store the pair-sum.
// ---------------------------------------------------------------------------
__global__ __launch_bounds__(64) void gru_level(
    const float* __restrict__ giop,  // [64][300] packed
    const float* __restrict__ Whp,   // [100][300] packed
    const float* __restrict__ Wirz,  // [18][200] packed
    const float* __restrict__ Win,   // [18][100] packed
    const float* __restrict__ bhhp,  // [100]
    const float* __restrict__ samp,  // (O,P,63,8)
    const float* __restrict__ addr,  // (O,P,63,10)
    const float* __restrict__ hin,   // [100][cells]
    float* __restrict__ hout,        // [100][cells/2] pairsum, or [100][cells] if last
    int lw, int first, int last)
{
    const int slice = blockIdx.y;
    const int c = blockIdx.x * NTH + threadIdx.x;
    const int w = 1 << lw;
    const int cells = 4096 << lw;
    const int op = c >> lw;
    const int node = w - 1 + (c & (w - 1));
    const int o = (blockIdx.x * NTH) >> (lw + 6);   // wave-uniform (scalar)

    // ---- per-cell inputs into registers (reused by two loops) ----
    float x[18];
    {
        const float4* sp4 = (const float4*)(samp + (size_t)(op * 63 + node) * 8);
        float4 s0 = sp4[0], s1 = sp4[1];
        x[0] = s0.x; x[1] = s0.y; x[2] = s0.z; x[3] = s0.w;
        x[4] = s1.x; x[5] = s1.y; x[6] = s1.z; x[7] = s1.w;
        const float2* ap2 = (const float2*)(addr + (size_t)(op * 63 + node) * 10);
        #pragma unroll
        for (int q = 0; q < 5; ++q) { float2 a = ap2[q]; x[8 + 2 * q] = a.x; x[9 + 2 * q] = a.y; }
    }

    const float* gb = giop + o * 300 + slice * 75;

    float ar[25], az[25], anh[25];
    #pragma unroll
    for (int i = 0; i < 25; ++i) { ar[i] = gb[i]; az[i] = gb[25 + i]; }

    // input contribution to r,z
    #pragma unroll 1
    for (int k = 0; k < 18; ++k) {
        const float* wr = Wirz + k * 200 + slice * 50;
        float xk = x[k];
        #pragma unroll
        for (int i = 0; i < 25; ++i) {
            ar[i] = fmaf(xk, wr[i], ar[i]);
            az[i] = fmaf(xk, wr[25 + i], az[i]);
        }
    }

    const float* bh = bhhp + slice * 25;
    #pragma unroll
    for (int i = 0; i < 25; ++i) anh[i] = bh[i];

    // fused hidden loop: r,z,nh in one pass, h read once per k
    if (!first) {
        const float* hc = hin + c;
        for (int k = 0; k < 100; ++k) {
            float hk = hc[(size_t)k * cells];
            const float* wr = Whp + k * 300 + slice * 75;
            #pragma unroll
            for (int i = 0; i < 25; ++i) {
                ar[i]  = fmaf(hk, wr[i],      ar[i]);
                az[i]  = fmaf(hk, wr[25 + i], az[i]);
                anh[i] = fmaf(hk, wr[50 + i], anh[i]);
            }
        }
    }

    // r = sigmoid(ar); t = r * anh; reuse ar as acc for i_n
    float tmuln[25];
    #pragma unroll
    for (int i = 0; i < 25; ++i) {
        float r = sigmoidf_(ar[i]);
        tmuln[i] = r * anh[i];
        ar[i] = gb[50 + i];
    }
    #pragma unroll 1
    for (int k = 0; k < 18; ++k) {
        const float* wr = Win + k * 100 + slice * 25;
        float xk = x[k];
        #pragma unroll
        for (int i = 0; i < 25; ++i) ar[i] = fmaf(xk, wr[i], ar[i]);
    }

    const int half = cells >> 1;
    #pragma unroll
    for (int i = 0; i < 25; ++i) {
        float n = tanhf_(ar[i] + tmuln[i]);
        float z = sigmoidf_(az[i]);
        float hcv = first ? 0.0f : hin[(size_t)(slice * 25 + i) * cells + c];
        float hv = (1.0f - z) * n + z * hcv;
        if (last) {
            hout[(size_t)(slice * 25 + i) * cells + c] = hv;
        } else {
            float hs = hv + __shfl_xor(hv, 1);
            if ((c & 1) == 0) hout[(size_t)(slice * 25 + i) * half + (c >> 1)] = hs;
        }
    }
}

// ---------------------------------------------------------------------------
// MLP head + logsumexp over the 64 particles. Block = one o (64 lanes = particles).
// ---------------------------------------------------------------------------
__global__ __launch_bounds__(64) void mlp_lse(
    const float* __restrict__ h0,   // [100][4096]
    const float* __restrict__ W1T,  // [100][50]
    const float* __restrict__ b1,
    const float* __restrict__ W2T,  // [50][25]
    const float* __restrict__ b2,
    const float* __restrict__ W3,   // [25]
    const float* __restrict__ b3,
    float* __restrict__ out)
{
    const int o = blockIdx.x;
    const int p = threadIdx.x;
    const int c = o * 64 + p;

    float y1[50];
    #pragma unroll
    for (int j = 0; j < 50; ++j) y1[j] = b1[j];
    #pragma unroll 2
    for (int g = 0; g < 100; ++g) {
        float rg = h0[(size_t)g * 4096 + c];
        const float* wr = W1T + g * 50;
        #pragma unroll
        for (int j = 0; j < 50; ++j) y1[j] = fmaf(rg, wr[j], y1[j]);
    }

    float y2[25];
    #pragma unroll
    for (int i = 0; i < 25; ++i) y2[i] = b2[i];
    #pragma unroll
    for (int j = 0; j < 50; ++j) {
        float v = fmaxf(y1[j], 0.0f);
        const float* wr = W2T + j * 25;
        #pragma unroll
        for (int i = 0; i < 25; ++i) y2[i] = fmaf(v, wr[i], y2[i]);
    }

    float cv = b3[0];
    #pragma unroll
    for (int i = 0; i < 25; ++i) cv = fmaf(fmaxf(y2[i], 0.0f), W3[i], cv);

    float m = cv;
    #pragma unroll
    for (int s = 1; s < 64; s <<= 1) m = fmaxf(m, __shfl_xor(m, s));
    float e = __expf(cv - m);
    #pragma unroll
    for (int s = 1; s < 64; s <<= 1) e += __shfl_xor(e, s);
    if (p == 0) out[o] = m + __logf(e) - 4.1588830833596715f; // log(64)
}

// ---------------------------------------------------------------------------
extern "C" void kernel_launch(void* const* d_in, const int* in_sizes, int n_in,
                              void* d_out, int out_size, void* d_ws, size_t ws_size,
                              hipStream_t stream)
{
    const float* obs  = (const float*)d_in[0];
    const float* samp = (const float*)d_in[1];
    const float* addr = (const float*)d_in[2];
    const float* W_ih = (const float*)d_in[3];
    const float* W_hh = (const float*)d_in[4];
    const float* b_ih = (const float*)d_in[5];
    const float* b_hh = (const float*)d_in[6];
    const float* W1   = (const float*)d_in[7];
    const float* b1   = (const float*)d_in[8];
    const float* W2   = (const float*)d_in[9];
    const float* b2   = (const float*)d_in[10];
    const float* W3   = (const float*)d_in[11];
    const float* b3   = (const float*)d_in[12];
    float* out = (float*)d_out;

    float* ws   = (float*)d_ws;
    float* giop = ws;              // 19200
    float* Whp  = ws + 19200;      // 30000
    float* Wirz = ws + 49200;      // 3600
    float* Win  = ws + 52800;      // 1800
    float* bhhp = ws + 54600;      // 100
    float* W1T  = ws + 54700;      // 5000
    float* W2T  = ws + 59700;      // 1250
    float* hA   = ws + 61440;      // 100 * 65536
    float* hB   = hA + 6553600;    // 100 * 32768

    precompute_kernel<<<(60950 + NTH - 1) / NTH, NTH, 0, stream>>>(
        obs, W_ih, W_hh, b_ih, b_hh, W1, W2,
        giop, Whp, Wirz, Win, bhhp, W1T, W2T);

    struct Lv { int lw; const float* hin; float* hout; int first; int last; };
    const Lv L[6] = {
        {5, hA, hA, 1, 0},   // level 5: h_child = 0, pairsum -> hA [100][65536]
        {4, hA, hB, 0, 0},   // -> hB [100][32768]
        {3, hB, hA, 0, 0},   // -> hA [100][16384]
        {2, hA, hB, 0, 0},   // -> hB [100][8192]
        {1, hB, hA, 0, 0},   // -> hA [100][4096]  (root's h_child)
        {0, hA, hB, 0, 1},   // root h -> hB [100][4096]
    };
    for (int i = 0; i < 6; ++i) {
        int cells = 4096 << L[i].lw;
        dim3 grid(cells / NTH, 4);
        gru_level<<<grid, NTH, 0, stream>>>(
            giop, Whp, Wirz, Win, bhhp, samp, addr,
            L[i].hin, L[i].hout, L[i].lw, L[i].first, L[i].last);
    }

    mlp_lse<<<64, NTH, 0, stream>>>(hB, W1T, b1, W2T, b2, W3, b3, out);
}